// Round 2
// baseline (1724.047 us; speedup 1.0000x reference)
//
#include <hip/hip_runtime.h>
#include <hip/hip_bf16.h>

typedef unsigned short u16;
typedef unsigned int u32;

#define DEVFN static __device__ __forceinline__

DEVFN float bfu(u32 u) { return __uint_as_float(u << 16); }
DEVFN u16 f2bu(float v) {
  u32 x = __float_as_uint(v);
  return (u16)((x + 0x7fffu + ((x >> 16) & 1u)) >> 16);
}

// =====================================================================
// Generic 1x1-conv GEMM:  out[b][co][n] = EP( gain[co]*acc + bias[co] )
//   acc = sum_k W[co][k] * XLOAD(k, n)
// XM: 0 plain f32, 2 plain f32 + relu-on-load,
//     3 conv3x3 implicit gather (K = ci*9+tap, from x3[b][64][128][128]),
//     4 depthwise3x3+bn+relu fused from bf16 qkv[b][512][128][128]
//     5 xx = relu(xr_conv + xc_conv + v) fused loader (k = ch 0..255)
// EP: 0 f32 store, 1 bf16 store, 2 hsigmoid*aux f32 store, 3 relu f32 store
// Tile: 64co x 64n, TK=16, block 256 threads, 4x4 microtile.
// =====================================================================
struct GemmP {
  const float* Xf;
  const float* W; const float* gain; const float* bias;
  float* outF; u16* outH; const float* aux;
  int CI; int N;
  const float* x3;
  const u16* dsrc; const float* wd; const float* gd; const float* bd;
  const float* xrc; const float* xcc;
};

template <int XM, int EP>
__launch_bounds__(256)
__global__ void gemm1x1(GemmP p) {
  __shared__ float Xs[16][64];
  __shared__ float Ws[16][64];
  const int b = blockIdx.z;
  const int n0 = blockIdx.x * 64;
  const int co0 = blockIdx.y * 64;
  const int t = threadIdx.x;
  const int tco = (t >> 4) << 2;
  const int tn = (t & 15) << 2;
  const int lk = t >> 4;          // 0..15 k-row for X load
  const int ln = (t & 15) << 2;   // n offset for X load
  const int wc = t >> 2;          // 0..63 co for W load
  const int wk = (t & 3) << 2;    // k for W load
  const int CI = p.CI, N = p.N;
  float acc[4][4] = {};

  for (int k0 = 0; k0 < CI; k0 += 16) {
    float v0, v1, v2, v3;
    if constexpr (XM == 0 || XM == 2) {
      const float* src = p.Xf + ((size_t)b * CI + (k0 + lk)) * N + n0 + ln;
      float4 r = *(const float4*)src;
      v0 = r.x; v1 = r.y; v2 = r.z; v3 = r.w;
      if constexpr (XM == 2) {
        v0 = fmaxf(v0, 0.f); v1 = fmaxf(v1, 0.f);
        v2 = fmaxf(v2, 0.f); v3 = fmaxf(v3, 0.f);
      }
    } else if constexpr (XM == 3) {
      const int k = k0 + lk;
      const int ci = k / 9;
      const int tap = k - ci * 9;
      const int dy = tap / 3 - 1;
      const int dx = tap - (tap / 3) * 3 - 1;
      const int y = (n0 >> 7) + dy;
      const int xb = (n0 & 127) + ln + dx;
      const float* src = p.x3 + ((size_t)b * 64 + ci) * 16384 + (size_t)y * 128;
      const bool yok = ((unsigned)y < 128u);
      v0 = (yok && (unsigned)(xb + 0) < 128u) ? src[xb + 0] : 0.f;
      v1 = (yok && (unsigned)(xb + 1) < 128u) ? src[xb + 1] : 0.f;
      v2 = (yok && (unsigned)(xb + 2) < 128u) ? src[xb + 2] : 0.f;
      v3 = (yok && (unsigned)(xb + 3) < 128u) ? src[xb + 3] : 0.f;
    } else if constexpr (XM == 4) { // depthwise 3x3 + bn + relu on the fly
      const int ci = k0 + lk;
      const int y = n0 >> 7;
      const int xb = (n0 & 127) + ln;
      const u16* src = p.dsrc + ((size_t)b * 512 + ci) * 16384;
      const float* wdp = p.wd + ci * 9;
      float s0 = 0.f, s1 = 0.f, s2 = 0.f, s3 = 0.f;
      #pragma unroll
      for (int dy = -1; dy <= 1; ++dy) {
        const int yy = y + dy;
        if ((unsigned)yy < 128u) {
          float tv[6];
          #pragma unroll
          for (int u = 0; u < 6; ++u) {
            const int xx = xb - 1 + u;
            tv[u] = ((unsigned)xx < 128u) ? bfu((u32)src[(size_t)yy * 128 + xx]) : 0.f;
          }
          const float w0 = wdp[(dy + 1) * 3 + 0];
          const float w1 = wdp[(dy + 1) * 3 + 1];
          const float w2 = wdp[(dy + 1) * 3 + 2];
          s0 += w0 * tv[0] + w1 * tv[1] + w2 * tv[2];
          s1 += w0 * tv[1] + w1 * tv[2] + w2 * tv[3];
          s2 += w0 * tv[2] + w1 * tv[3] + w2 * tv[4];
          s3 += w0 * tv[3] + w1 * tv[4] + w2 * tv[5];
        }
      }
      const float g = p.gd[ci], bb = p.bd[ci];
      v0 = fmaxf(g * s0 + bb, 0.f);
      v1 = fmaxf(g * s1 + bb, 0.f);
      v2 = fmaxf(g * s2 + bb, 0.f);
      v3 = fmaxf(g * s3 + bb, 0.f);
    } else { // XM == 5: xx = relu(xr_conv[cc,a] + xc_conv[cc,bb] + v)
      const int ch = k0 + lk;       // 0..255
      const int y = n0 >> 7;
      const int x0i = (n0 & 127) + ln;
      const int cc = y >> 3;
      const int abase = (y & 7) << 2;
      const u16* vsrc = p.dsrc + (((size_t)b * 512 + 256 + ch) * 128 + y) * 128;
      const float* xr = p.xrc + ((size_t)b * 256 + ch) * 512 + cc * 32;
      const float* xc = p.xcc + ((size_t)b * 256 + ch) * 512 + cc * 32;
      uint2 r = *(const uint2*)(vsrc + x0i);
      float vv0 = bfu(r.x & 0xffffu), vv1 = bfu(r.x >> 16);
      float vv2 = bfu(r.y & 0xffffu), vv3 = bfu(r.y >> 16);
      v0 = fmaxf(xr[abase + ((x0i + 0) >> 5)] + xc[(x0i + 0) & 31] + vv0, 0.f);
      v1 = fmaxf(xr[abase + ((x0i + 1) >> 5)] + xc[(x0i + 1) & 31] + vv1, 0.f);
      v2 = fmaxf(xr[abase + ((x0i + 2) >> 5)] + xc[(x0i + 2) & 31] + vv2, 0.f);
      v3 = fmaxf(xr[abase + ((x0i + 3) >> 5)] + xc[(x0i + 3) & 31] + vv3, 0.f);
    }
    Xs[lk][ln + 0] = v0; Xs[lk][ln + 1] = v1;
    Xs[lk][ln + 2] = v2; Xs[lk][ln + 3] = v3;
    {
      const float* src = p.W + (size_t)(co0 + wc) * CI + k0 + wk;
      float4 r = *(const float4*)src;
      Ws[wk + 0][wc] = r.x; Ws[wk + 1][wc] = r.y;
      Ws[wk + 2][wc] = r.z; Ws[wk + 3][wc] = r.w;
    }
    __syncthreads();
    #pragma unroll
    for (int kk = 0; kk < 16; ++kk) {
      const float4 a4 = *(const float4*)&Ws[kk][tco];
      const float4 b4 = *(const float4*)&Xs[kk][tn];
      acc[0][0] += a4.x * b4.x; acc[0][1] += a4.x * b4.y;
      acc[0][2] += a4.x * b4.z; acc[0][3] += a4.x * b4.w;
      acc[1][0] += a4.y * b4.x; acc[1][1] += a4.y * b4.y;
      acc[1][2] += a4.y * b4.z; acc[1][3] += a4.y * b4.w;
      acc[2][0] += a4.z * b4.x; acc[2][1] += a4.z * b4.y;
      acc[2][2] += a4.z * b4.z; acc[2][3] += a4.z * b4.w;
      acc[3][0] += a4.w * b4.x; acc[3][1] += a4.w * b4.y;
      acc[3][2] += a4.w * b4.z; acc[3][3] += a4.w * b4.w;
    }
    __syncthreads();
  }

  const int CO = (int)gridDim.y * 64;
  #pragma unroll
  for (int i = 0; i < 4; ++i) {
    const int co = co0 + tco + i;
    const float g = p.gain[co], bb = p.bias[co];
    const size_t oidx = ((size_t)b * CO + co) * N + n0 + tn;
    float o0 = g * acc[i][0] + bb;
    float o1 = g * acc[i][1] + bb;
    float o2 = g * acc[i][2] + bb;
    float o3 = g * acc[i][3] + bb;
    if constexpr (EP == 3) {
      o0 = fmaxf(o0, 0.f); o1 = fmaxf(o1, 0.f);
      o2 = fmaxf(o2, 0.f); o3 = fmaxf(o3, 0.f);
    }
    if constexpr (EP == 2) {
      const float4 ax = *(const float4*)(p.aux + oidx);
      o0 = fminf(fmaxf(o0 + 3.f, 0.f), 6.f) * (1.f / 6.f) * ax.x;
      o1 = fminf(fmaxf(o1 + 3.f, 0.f), 6.f) * (1.f / 6.f) * ax.y;
      o2 = fminf(fmaxf(o2 + 3.f, 0.f), 6.f) * (1.f / 6.f) * ax.z;
      o3 = fminf(fmaxf(o3 + 3.f, 0.f), 6.f) * (1.f / 6.f) * ax.w;
    }
    if constexpr (EP == 1) {
      u32 wlo = (u32)f2bu(o0) | ((u32)f2bu(o1) << 16);
      u32 whi = (u32)f2bu(o2) | ((u32)f2bu(o3) << 16);
      *(uint2*)(p.outH + oidx) = make_uint2(wlo, whi);
    } else {
      *(float4*)(p.outF + oidx) = make_float4(o0, o1, o2, o3);
    }
  }
}

// ============== pack wq/wk/wv -> Wqkv[512][128], gains/biases ==============
__global__ void pack_qkv(const float* wq, const float* wk, const float* wv,
                         const float* gq, const float* bq,
                         const float* gk, const float* bk,
                         const float* gv, const float* bv,
                         float* W, float* g, float* b) {
  int t = blockIdx.x * 256 + threadIdx.x; // 0..32767
  if (t < 16384) { W[t] = wq[t]; W[16384 + t] = wk[t]; }
  W[32768 + t] = wv[t];
  if (t < 128) { g[t] = gq[t]; b[t] = bq[t]; g[128 + t] = gk[t]; b[128 + t] = bk[t]; }
  if (t < 256) { g[256 + t] = gv[t]; b[256 + t] = bv[t]; }
}

// ============== cf = relu(bn(conv1x1(cb, wen)))  [B,8,16384] ==============
__global__ void cf_kernel(const float* cb, const float* wen, const float* gen,
                          const float* ben, float* cf) {
  __shared__ float w[8][128];
  const int t = threadIdx.x;
  for (int i = t; i < 1024; i += 256) w[i >> 7][i & 127] = wen[i];
  __syncthreads();
  const int b = blockIdx.y;
  const int n = blockIdx.x * 256 + t;
  const float* xb = cb + (size_t)b * 128 * 16384 + n;
  float acc[8] = {};
  for (int ci = 0; ci < 128; ++ci) {
    const float xv = xb[(size_t)ci * 16384];
    #pragma unroll
    for (int k = 0; k < 8; ++k) acc[k] += w[k][ci] * xv;
  }
  #pragma unroll
  for (int k = 0; k < 8; ++k)
    cf[((size_t)b * 8 + k) * 16384 + n] = fmaxf(gen[k] * acc[k] + ben[k], 0.f);
}

// ====== CCAM: e[b,c,k]=sum_n cb*cf ; a = softmax(max_k e - e) over k ======
__global__ void ccam_attn(const float* cb, const float* cf, float* a) {
  const int b = blockIdx.x >> 7;
  const int c = blockIdx.x & 127;
  const int t = threadIdx.x;
  const float* xr = cb + ((size_t)b * 128 + c) * 16384;
  const float* yb = cf + (size_t)b * 8 * 16384;
  float pr[8] = {};
  for (int n = t; n < 16384; n += 256) {
    const float xv = xr[n];
    #pragma unroll
    for (int k = 0; k < 8; ++k) pr[k] += xv * yb[k * 16384 + n];
  }
  __shared__ float red[8][256];
  #pragma unroll
  for (int k = 0; k < 8; ++k) red[k][t] = pr[k];
  __syncthreads();
  for (int s = 128; s > 0; s >>= 1) {
    if (t < s) {
      #pragma unroll
      for (int k = 0; k < 8; ++k) red[k][t] += red[k][t + s];
    }
    __syncthreads();
  }
  if (t == 0) {
    float e[8], m = -1e30f;
    #pragma unroll
    for (int k = 0; k < 8; ++k) { e[k] = red[k][0]; m = fmaxf(m, e[k]); }
    float mt = -1e30f;
    #pragma unroll
    for (int k = 0; k < 8; ++k) mt = fmaxf(mt, m - e[k]);
    float s = 0.f, pk[8];
    #pragma unroll
    for (int k = 0; k < 8; ++k) { pk[k] = __expf(m - e[k] - mt); s += pk[k]; }
    const float inv = 1.f / s;
    #pragma unroll
    for (int k = 0; k < 8; ++k) a[((size_t)b * 128 + c) * 8 + k] = pk[k] * inv;
  }
}

// ============== xs = cb + sc * (a @ cf)   (in place on cb) ==============
__global__ void ccam_apply(float* cb, const float* cf, const float* a, const float* sc) {
  const int bc = blockIdx.y;
  const int b = bc >> 7;
  const int n = blockIdx.x * 256 + threadIdx.x;
  __shared__ float ak[8];
  if (threadIdx.x < 8) ak[threadIdx.x] = a[(size_t)bc * 8 + threadIdx.x];
  __syncthreads();
  const float* yb = cf + (size_t)b * 8 * 16384 + n;
  float dec = 0.f;
  #pragma unroll
  for (int k = 0; k < 8; ++k) dec += ak[k] * yb[k * 16384];
  const size_t idx = (size_t)bc * 16384 + n;
  cb[idx] = cb[idx] + sc[0] * dec;
}

// ====== row shunt: sr[b][j][c][h] = mean_w4 qkv[b][c][h][w4*4+j] ======
__global__ void shunt_row(const u16* qkv, float* sr) {
  const int idx = blockIdx.x * 256 + threadIdx.x; // (b,c,h): 8*512*128
  const int h = idx & 127;
  const int c = (idx >> 7) & 511;
  const int b = idx >> 16;
  const uint4* src = (const uint4*)(qkv + (((size_t)b * 512 + c) * 128 + h) * 128);
  float s0 = 0.f, s1 = 0.f, s2 = 0.f, s3 = 0.f;
  #pragma unroll
  for (int w8 = 0; w8 < 16; ++w8) {
    const uint4 u = src[w8];
    s0 += bfu(u.x & 0xffffu) + bfu(u.z & 0xffffu);
    s1 += bfu(u.x >> 16)     + bfu(u.z >> 16);
    s2 += bfu(u.y & 0xffffu) + bfu(u.w & 0xffffu);
    s3 += bfu(u.y >> 16)     + bfu(u.w >> 16);
  }
  const size_t base = (((size_t)b * 4) * 512 + c) * 128 + h;
  sr[base + 0 * 512 * 128] = s0 * (1.f / 32.f);
  sr[base + 1 * 512 * 128] = s1 * (1.f / 32.f);
  sr[base + 2 * 512 * 128] = s2 * (1.f / 32.f);
  sr[base + 3 * 512 * 128] = s3 * (1.f / 32.f);
}

// ====== col shunt: sc[b][jc][c][w] = mean_hr qkv[b][c][jc*32+hr][w] ======
__global__ void shunt_col(const u16* qkv, float* scv) {
  const int idx = blockIdx.x * 256 + threadIdx.x; // (b,jc,c,w): 8*4*512*128
  const int w = idx & 127;
  const int c = (idx >> 7) & 511;
  const int jc = (idx >> 16) & 3;
  const int b = idx >> 18;
  const u16* src = qkv + (((size_t)b * 512 + c) * 128 + jc * 32) * 128 + w;
  float s = 0.f;
  #pragma unroll
  for (int hr = 0; hr < 32; ++hr) s += bfu((u32)src[hr * 128]);
  scv[idx] = s * (1.f / 32.f);
}

// ============ axial attention (row or col; identical math) ============
// sall [B][4][512][128]: ch 0..127 = q, 128..255 = k, 256..511 = v
// out [B][256][512]: out[b][h*32+d][jc*128 + r]
DEVFN float pinterp(const float* pos, int j, int ch, int col) {
  const float s = (col + 0.5f) * 0.125f - 0.5f;
  const float fl = floorf(s);
  const int i0 = (int)fl;
  const float f = s - fl;
  const int ia = i0 < 0 ? 0 : (i0 > 15 ? 15 : i0);
  const int i1 = i0 + 1;
  const int ib = i1 < 0 ? 0 : (i1 > 15 ? 15 : i1);
  const float* pp = pos + ((size_t)j * 128 + ch) * 16;
  return pp[ia] * (1.f - f) + pp[ib] * f;
}

__global__ void axial(const float* sall, const float* posq, const float* posk,
                      float* out) {
  __shared__ float kl[16][128];
  __shared__ float vl[32][128];
  const int blk = blockIdx.x;           // (b, jc, h)
  const int h = blk & 7;
  const int jc = (blk >> 3) & 3;
  const int b = blk >> 5;
  const int r = threadIdx.x;            // 0..127 (L position)
  const float* base = sall + ((size_t)b * 4 + jc) * 512 * 128;
  for (int i = r; i < 16 * 128; i += 128) {
    const int kd = i >> 7, col = i & 127;
    kl[kd][col] = base[(128 + h * 16 + kd) * 128 + col] + pinterp(posk, jc, h * 16 + kd, col);
  }
  for (int i = r; i < 32 * 128; i += 128) {
    const int d = i >> 7, col = i & 127;
    vl[d][col] = base[(256 + h * 32 + d) * 128 + col];
  }
  __syncthreads();
  float q[16];
  #pragma unroll
  for (int kd = 0; kd < 16; ++kd)
    q[kd] = base[(h * 16 + kd) * 128 + r] + pinterp(posq, jc, h * 16 + kd, r);
  // pass 1: row max
  float m = -1e30f;
  for (int col = 0; col < 128; ++col) {
    float s = 0.f;
    #pragma unroll
    for (int kd = 0; kd < 16; ++kd) s += q[kd] * kl[kd][col];
    m = fmaxf(m, s * 0.25f);
  }
  // pass 2: exp + accumulate denom and PV
  float den = 0.f;
  float acc[32] = {};
  for (int col = 0; col < 128; ++col) {
    float s = 0.f;
    #pragma unroll
    for (int kd = 0; kd < 16; ++kd) s += q[kd] * kl[kd][col];
    const float pv = __expf(s * 0.25f - m);
    den += pv;
    #pragma unroll
    for (int d = 0; d < 32; ++d) acc[d] += pv * vl[d][col];
  }
  const float inv = 1.f / den;
  float* ob = out + ((size_t)b * 256 + h * 32) * 512 + (size_t)jc * 128 + r;
  #pragma unroll
  for (int d = 0; d < 32; ++d) ob[(size_t)d * 512] = acc[d] * inv;
}

// =====================================================================
extern "C" void kernel_launch(void* const* d_in, const int* in_sizes, int n_in,
                              void* d_out, int out_size, void* d_ws, size_t ws_size,
                              hipStream_t stream) {
  const float* x   = (const float*)d_in[0];
  const float* wcc = (const float*)d_in[1];
  const float* gcc = (const float*)d_in[2];
  const float* bcc = (const float*)d_in[3];
  const float* wen = (const float*)d_in[4];
  const float* gen = (const float*)d_in[5];
  const float* ben = (const float*)d_in[6];
  const float* sc  = (const float*)d_in[7];
  const float* wq  = (const float*)d_in[8];
  const float* gq  = (const float*)d_in[9];
  const float* bq  = (const float*)d_in[10];
  const float* wk  = (const float*)d_in[11];
  const float* gk  = (const float*)d_in[12];
  const float* bk  = (const float*)d_in[13];
  const float* wv  = (const float*)d_in[14];
  const float* gv  = (const float*)d_in[15];
  const float* bv  = (const float*)d_in[16];
  const float* wd  = (const float*)d_in[17];
  const float* gd  = (const float*)d_in[18];
  const float* bd  = (const float*)d_in[19];
  const float* wp  = (const float*)d_in[20];
  const float* gp  = (const float*)d_in[21];
  const float* bp  = (const float*)d_in[22];
  const float* wr  = (const float*)d_in[23];
  const float* gr  = (const float*)d_in[24];
  const float* brr = (const float*)d_in[25];
  const float* wc2 = (const float*)d_in[26];
  const float* gc2 = (const float*)d_in[27];
  const float* bc2 = (const float*)d_in[28];
  const float* wo  = (const float*)d_in[29];
  const float* go  = (const float*)d_in[30];
  const float* bo  = (const float*)d_in[31];
  const float* prq = (const float*)d_in[32];
  const float* prk = (const float*)d_in[33];
  const float* pcq = (const float*)d_in[34];
  const float* pck = (const float*)d_in[35];

  char* ws = (char*)d_ws;
  // ---- workspace map (bytes), total = 205,819,904 (~196.3 MB) ----
  u16*   qkv     = (u16*)  (ws + 0);            // 134217728  [B,512,16384] bf16
  char*  region  = ws + 134217728;              // 67108864: cb f32 (steps 2-6), then axial scratch
  float* cb      = (float*)region;              //   [B,128,16384] f32
  float* sr_all  = (float*)(region + 0);        //   8388608  [B,4,512,128] f32 (after cb dead)
  float* sc_all  = (float*)(region + 8388608);  //   8388608
  float* xr_lin  = (float*)(region + 16777216); //   4194304  [B,256,512] f32
  float* xc_lin  = (float*)(region + 20971520); //   4194304
  float* xr_conv = (float*)(region + 25165824); //   4194304
  float* xc_conv = (float*)(region + 29360128); //   4194304
  float* cf      = (float*)(ws + 201326592);    // 4194304   [B,8,16384] f32
  float* abuf    = (float*)(ws + 205520896);    // 32768     [B,128,8] f32
  float* Wqkv    = (float*)(ws + 205553664);    // 262144    [512,128]
  float* gqkv    = (float*)(ws + 205815808);    // 2048
  float* bqkv    = (float*)(ws + 205817856);    // 2048
  float* qkvp    = (float*)d_out;               // [B,128,16384] f32 lives in d_out until final GEMM
  float* out     = (float*)d_out;

  // 1. pack qkv weights
  pack_qkv<<<128, 256, 0, stream>>>(wq, wk, wv, gq, bq, gk, bk, gv, bv, Wqkv, gqkv, bqkv);

  // 2. cb = relu(bn(conv3x3(x, wcc)))  — implicit GEMM, K=576
  { GemmP p{}; p.x3 = x; p.W = wcc; p.gain = gcc; p.bias = bcc; p.outF = cb;
    p.CI = 576; p.N = 16384;
    gemm1x1<3, 3><<<dim3(256, 2, 8), 256, 0, stream>>>(p); }

  // 3. cf = relu(bn(conv1x1(cb, wen)))
  cf_kernel<<<dim3(64, 8), 256, 0, stream>>>(cb, wen, gen, ben, cf);

  // 4-5. CCAM: a = softmax(max-e) ; cb <- cb + sc*dec  (xs in place)
  ccam_attn<<<1024, 256, 0, stream>>>(cb, cf, abuf);
  ccam_apply<<<dim3(64, 1024), 256, 0, stream>>>(cb, cf, abuf, sc);

  // 6. qkv = bn(conv1x1(xs, [wq;wk;wv]))  -> bf16 [B,512,16384]
  { GemmP p{}; p.Xf = cb; p.W = Wqkv; p.gain = gqkv; p.bias = bqkv; p.outH = qkv;
    p.CI = 128; p.N = 16384;
    gemm1x1<0, 1><<<dim3(256, 8, 8), 256, 0, stream>>>(p); }

  // 7. shunts (row + col) over all 512 channels  (cb region now dead -> reuse)
  shunt_row<<<2048, 256, 0, stream>>>(qkv, sr_all);
  shunt_col<<<8192, 256, 0, stream>>>(qkv, sc_all);

  // 8. qkvp = bn(conv1x1(relu(bn(dwconv3x3(qkv))), wp)) -> d_out
  { GemmP p{}; p.dsrc = qkv; p.wd = wd; p.gd = gd; p.bd = bd;
    p.W = wp; p.gain = gp; p.bias = bp; p.outF = qkvp;
    p.CI = 512; p.N = 16384;
    gemm1x1<4, 0><<<dim3(256, 2, 8), 256, 0, stream>>>(p); }

  // 9. axial attentions
  axial<<<256, 128, 0, stream>>>(sr_all, prq, prk, xr_lin);
  axial<<<256, 128, 0, stream>>>(sc_all, pcq, pck, xc_lin);

  // 10. xr_conv = bn(conv1x1(relu(xr_lin), wr)) ; same for col
  { GemmP p{}; p.Xf = xr_lin; p.W = wr; p.gain = gr; p.bias = brr; p.outF = xr_conv;
    p.CI = 256; p.N = 512;
    gemm1x1<2, 0><<<dim3(8, 4, 8), 256, 0, stream>>>(p); }
  { GemmP p{}; p.Xf = xc_lin; p.W = wc2; p.gain = gc2; p.bias = bc2; p.outF = xc_conv;
    p.CI = 256; p.N = 512;
    gemm1x1<2, 0><<<dim3(8, 4, 8), 256, 0, stream>>>(p); }

  // 11+12. out = hsigmoid(bn(conv1x1(relu(xr+xc+v), wo))) * qkvp
  //        (xx built on the fly in the loader; aux read == out write index)
  { GemmP p{}; p.dsrc = qkv; p.xrc = xr_conv; p.xcc = xc_conv;
    p.W = wo; p.gain = go; p.bias = bo; p.aux = qkvp; p.outF = out;
    p.CI = 256; p.N = 16384;
    gemm1x1<5, 2><<<dim3(256, 2, 8), 256, 0, stream>>>(p); }
}

// Round 5
// 1503.478 us; speedup vs baseline: 1.1467x; 1.1467x over previous
//
#include <hip/hip_runtime.h>
#include <hip/hip_bf16.h>

typedef unsigned short u16;
typedef unsigned int u32;
typedef __attribute__((ext_vector_type(8))) short bf16x8;
typedef __attribute__((ext_vector_type(4))) float f32x4;

#define DEVFN static __device__ __forceinline__

DEVFN float bfu(u32 u) { return __uint_as_float(u << 16); }
DEVFN u16 f2bu(float v) {
  u32 x = __float_as_uint(v);
  return (u16)((x + 0x7fffu + ((x >> 16) & 1u)) >> 16);
}
DEVFN float bfe(bf16x8 v, int j) { return bfu((u32)(u16)v[j]); }

// =====================================================================
// MFMA GEMM, NHWC:  D[n][co] = EP( gain[co] * (sum_k X[n][k]*W[co][k]) + bias[co] )
// A = X (M=n, K-contiguous, direct global b128 loads)
// B = W[co][k] bf16 (staged in LDS, 64co x 64k per stage)
// Block: 256 thr (4 waves 2x2), tile 128n x 64co, mfma_f32_16x16x32_bf16.
// LD: 0 plain bf16 NHWC, 1 conv3x3 gather from xt (K' = tap*64+ci), 2 xx-fused
// EP: 0 bf16 store, 1 relu+bf16 store, 2 hsigmoid*qkvp -> NCHW f32 (d_out)
// BM: 0 normal (b = blockIdx.z), 1 per-batch (X b=0, out b=b0)
// =====================================================================
struct GP {
  const u16* X; const u16* W;
  const u16* Xv; const u16* Xr; const u16* Xc;  // LD=2 inputs
  const u16* auxh;                               // qkvp (EP=2)
  u16* out; float* outf;
  const float* gain; const float* bias;
  int K; int NX; int CO; int b0;
};

template <int LD, int EP, int BM>
__launch_bounds__(256)
__global__ void gmm(GP p) {
  __shared__ u16 Ws[64 * 72];   // 64 co rows, pitch 72 bf16 (holds 64 k)
  const int t = threadIdx.x;
  const int lane = t & 63, wid = t >> 6;
  const int wn = (wid >> 1) << 6;    // wave n offset: 0 / 64
  const int wco = (wid & 1) << 5;    // wave co offset: 0 / 32
  const int l15 = lane & 15, lg = lane >> 4;
  const int n0 = blockIdx.x << 7;
  const int co0 = blockIdx.y << 6;
  const int b = (BM == 1) ? 0 : blockIdx.z;
  const int bo = (BM == 1) ? p.b0 : blockIdx.z;
  const int K = p.K;

  f32x4 acc[4][2];
  #pragma unroll
  for (int f = 0; f < 4; ++f)
    #pragma unroll
    for (int c = 0; c < 2; ++c) acc[f][c] = (f32x4){0.f, 0.f, 0.f, 0.f};

  const int sco = t >> 2, sks = (t & 3) << 4;
  const u16* wrow = p.W + (size_t)(co0 + sco) * K + sks;

  for (int kb = 0; kb < K; kb += 64) {
    __syncthreads();
    *(bf16x8*)&Ws[sco * 72 + sks] = *(const bf16x8*)(wrow + kb);
    *(bf16x8*)&Ws[sco * 72 + sks + 8] = *(const bf16x8*)(wrow + kb + 8);
    __syncthreads();
    #pragma unroll
    for (int ks = 0; ks < 64; ks += 32) {
      const int k0 = kb + ks;
      bf16x8 bfr[2];
      bfr[0] = *(const bf16x8*)&Ws[(wco + l15) * 72 + ks + lg * 8];
      bfr[1] = *(const bf16x8*)&Ws[(wco + 16 + l15) * 72 + ks + lg * 8];
      bf16x8 af[4];
      if constexpr (LD == 0) {
        const size_t rb = (size_t)(b * p.NX + n0 + wn + l15);
        #pragma unroll
        for (int f = 0; f < 4; ++f)
          af[f] = *(const bf16x8*)(p.X + (rb + f * 16) * K + k0 + lg * 8);
      } else if constexpr (LD == 1) {
        // conv3x3 im2col from xt [b][128][128][64], K' = tap*64 + ci
        const int tap = k0 >> 6;
        const int dy = tap / 3 - 1, dxt = tap - (tap / 3) * 3 - 1;
        const int yy = blockIdx.x + dy;
        const int ci0 = (k0 & 63) + lg * 8;
        if ((unsigned)yy < 128u) {
          #pragma unroll
          for (int f = 0; f < 4; ++f) {
            const int xv = wn + f * 16 + l15 + dxt;
            bf16x8 t8 = {};
            if ((unsigned)xv < 128u)
              t8 = *(const bf16x8*)(p.X + (((size_t)(b * 128 + yy) * 128 + xv) << 6) + ci0);
            af[f] = t8;
          }
        } else {
          #pragma unroll
          for (int f = 0; f < 4; ++f) af[f] = (bf16x8){};
        }
      } else {
        // xx = relu(xr_cv[pos_r][ch] + xc_cv[pos_c][ch] + v[n][ch])
        const int y = blockIdx.x;
        const int prb = ((y >> 3) << 5) + ((y & 7) << 2);
        const int pcb = (y >> 3) << 5;
        const int ch0 = k0 + lg * 8;
        #pragma unroll
        for (int f = 0; f < 4; ++f) {
          const int x = wn + f * 16 + l15;
          const int nn = n0 + x;
          bf16x8 v8 = *(const bf16x8*)(p.Xv + ((size_t)(b * 16384 + nn) << 9) + 256 + ch0);
          bf16x8 r8 = *(const bf16x8*)(p.Xr + ((size_t)(b * 512 + prb + (x >> 5)) << 8) + ch0);
          bf16x8 c8 = *(const bf16x8*)(p.Xc + ((size_t)(b * 512 + pcb + (x & 31)) << 8) + ch0);
          bf16x8 av;
          #pragma unroll
          for (int j = 0; j < 8; ++j) {
            float s = bfe(v8, j) + bfe(r8, j) + bfe(c8, j);
            av[j] = (short)f2bu(fmaxf(s, 0.f));
          }
          af[f] = av;
        }
      }
      #pragma unroll
      for (int f = 0; f < 4; ++f)
        #pragma unroll
        for (int c = 0; c < 2; ++c)
          acc[f][c] = __builtin_amdgcn_mfma_f32_16x16x32_bf16(af[f], bfr[c], acc[f][c], 0, 0, 0);
    }
  }

  // epilogue: D row n = (lg*4 + r), col co = l15
  #pragma unroll
  for (int c = 0; c < 2; ++c) {
    const int co = co0 + wco + (c << 4) + l15;
    const float g = p.gain[co], bb = p.bias[co];
    #pragma unroll
    for (int f = 0; f < 4; ++f) {
      const int nnb = n0 + wn + (f << 4) + (lg << 2);
      #pragma unroll
      for (int r = 0; r < 4; ++r) {
        float o = g * acc[f][c][r] + bb;
        const int nn = nnb + r;
        if constexpr (EP == 1) o = fmaxf(o, 0.f);
        if constexpr (EP == 2) {
          o = fminf(fmaxf(o + 3.f, 0.f), 6.f) * (1.f / 6.f);
          const float q = bfu((u32)p.auxh[((size_t)(bo * 16384 + nn) << 7) + co]);
          p.outf[((size_t)(bo * 128 + co) << 14) + nn] = o * q;
        } else {
          p.out[(size_t)(bo * p.NX + nn) * p.CO + co] = f2bu(o);
        }
      }
    }
  }
}

// ================= pack: weights -> bf16 (+ k-reorder), zero ebuf =================
__global__ void pack_k(const float* wcc, const float* wq, const float* wk, const float* wv,
                       const float* gq, const float* gk, const float* gv,
                       const float* bq, const float* bk, const float* bv,
                       const float* wp, const float* wr, const float* wc2, const float* wo,
                       u16* Wp3, u16* Wqkv, u16* Wwp, u16* Wwr, u16* Wwc, u16* Wwo,
                       float* gqkv, float* bqkv, float* ebuf) {
  int i = blockIdx.x * 256 + threadIdx.x;
  if (i < 73728) {  // Wp3[co][tap*64+ci] = wcc[co][ci][tap]
    const int co = i / 576, k = i - co * 576;
    const int tap = k >> 6, ci = k & 63;
    Wp3[i] = f2bu(wcc[(co * 64 + ci) * 9 + tap]);
    return;
  }
  i -= 73728;
  if (i < 65536) {
    const int co = i >> 7, ci = i & 127;
    const float v = co < 128 ? wq[co * 128 + ci]
                  : (co < 256 ? wk[(co - 128) * 128 + ci] : wv[(co - 256) * 128 + ci]);
    Wqkv[i] = f2bu(v);
    return;
  }
  i -= 65536;
  if (i < 65536) { Wwp[i] = f2bu(wp[i]); return; }
  i -= 65536;
  if (i < 65536) { Wwr[i] = f2bu(wr[i]); return; }
  i -= 65536;
  if (i < 65536) { Wwc[i] = f2bu(wc2[i]); return; }
  i -= 65536;
  if (i < 32768) { Wwo[i] = f2bu(wo[i]); return; }
  i -= 32768;
  if (i < 512) { gqkv[i] = i < 128 ? gq[i] : (i < 256 ? gk[i - 128] : gv[i - 256]); return; }
  i -= 512;
  if (i < 512) { bqkv[i] = i < 128 ? bq[i] : (i < 256 ? bk[i - 128] : bv[i - 256]); return; }
  i -= 512;
  if (i < 8192) ebuf[i] = 0.f;
}

// ============ x NCHW f32 [8][64][128][128] -> xt NHWC bf16 [8][128][128][64] ============
__global__ void xt_k(const float* x, u16* xt) {
  __shared__ u16 tile[64 * 130];
  const int y = blockIdx.x, b = blockIdx.y;
  const int t = threadIdx.x;
  {
    const int ci = t >> 2, xseg = (t & 3) * 32;
    const float* src = x + ((size_t)(b * 64 + ci) * 128 + y) * 128 + xseg;
    #pragma unroll
    for (int j = 0; j < 16; ++j) {
      const float2 f2 = *(const float2*)(src + j * 2);
      *(u32*)&tile[ci * 130 + xseg + 2 * j] = (u32)f2bu(f2.x) | ((u32)f2bu(f2.y) << 16);
    }
  }
  __syncthreads();
  const int xx = t >> 1, ch = (t & 1) * 32;
  u16* dst = xt + (((size_t)(b * 128 + y) * 128 + xx) << 6) + ch;
  uint4 q0, q1;
  #pragma unroll
  for (int h = 0; h < 2; ++h) {
    const int cb0 = ch + h * 16;
    u32 w0 = (u32)tile[(cb0 + 0) * 130 + xx] | ((u32)tile[(cb0 + 1) * 130 + xx] << 16);
    u32 w1 = (u32)tile[(cb0 + 2) * 130 + xx] | ((u32)tile[(cb0 + 3) * 130 + xx] << 16);
    u32 w2 = (u32)tile[(cb0 + 4) * 130 + xx] | ((u32)tile[(cb0 + 5) * 130 + xx] << 16);
    u32 w3 = (u32)tile[(cb0 + 6) * 130 + xx] | ((u32)tile[(cb0 + 7) * 130 + xx] << 16);
    u32 w4 = (u32)tile[(cb0 + 8) * 130 + xx] | ((u32)tile[(cb0 + 9) * 130 + xx] << 16);
    u32 w5 = (u32)tile[(cb0 + 10) * 130 + xx] | ((u32)tile[(cb0 + 11) * 130 + xx] << 16);
    u32 w6 = (u32)tile[(cb0 + 12) * 130 + xx] | ((u32)tile[(cb0 + 13) * 130 + xx] << 16);
    u32 w7 = (u32)tile[(cb0 + 14) * 130 + xx] | ((u32)tile[(cb0 + 15) * 130 + xx] << 16);
    if (h == 0) { q0 = make_uint4(w0, w1, w2, w3); q1 = make_uint4(w4, w5, w6, w7); }
    else {
      *(uint4*)(dst) = q0; *(uint4*)(dst + 8) = q1;
      *(uint4*)(dst + 16) = make_uint4(w0, w1, w2, w3);
      *(uint4*)(dst + 24) = make_uint4(w4, w5, w6, w7);
    }
  }
}

// ====== cf[n][8] = relu(gen*conv1x1(cb,wen)+ben), cb NHWC bf16 [n][128] ======
__global__ void cf_k(const u16* cb, const float* wen, const float* gen,
                     const float* ben, u16* cf) {
  __shared__ float wsm[1024];
  const int t = threadIdx.x;
  for (int i = t; i < 1024; i += 256) wsm[i] = wen[i];
  __syncthreads();
  const int n = blockIdx.x * 256 + t;
  const u16* row = cb + ((size_t)n << 7);
  float acc[8] = {};
  #pragma unroll 4
  for (int i = 0; i < 16; ++i) {
    const bf16x8 v = *(const bf16x8*)(row + i * 8);
    #pragma unroll
    for (int j = 0; j < 8; ++j) {
      const float xv = bfe(v, j);
      #pragma unroll
      for (int k = 0; k < 8; ++k) acc[k] += wsm[k * 128 + i * 8 + j] * xv;
    }
  }
  u32 o[4];
  #pragma unroll
  for (int k = 0; k < 4; ++k) {
    const float a = fmaxf(gen[2 * k] * acc[2 * k] + ben[2 * k], 0.f);
    const float bb = fmaxf(gen[2 * k + 1] * acc[2 * k + 1] + ben[2 * k + 1], 0.f);
    o[k] = (u32)f2bu(a) | ((u32)f2bu(bb) << 16);
  }
  *(uint4*)(cf + ((size_t)n << 3)) = make_uint4(o[0], o[1], o[2], o[3]);
}

// ====== ccam e: e[b][c][k] += sum_n cb[n][c]*cf[n][k] (atomic partials) ======
__global__ void ccam_e(const u16* cb, const u16* cf, float* ebuf) {
  const int chunk = blockIdx.x, b = blockIdx.y;
  const int t = threadIdx.x;
  const int c = t & 127, kh = (t >> 7) * 4;
  const int nb = b * 16384 + chunk * 512;
  float a0 = 0.f, a1 = 0.f, a2 = 0.f, a3 = 0.f;
  for (int i = 0; i < 512; ++i) {
    const size_t n = (size_t)(nb + i);
    const float xv = bfu((u32)cb[(n << 7) + c]);
    const u32 p0 = *(const u32*)(cf + (n << 3) + kh);
    const u32 p1 = *(const u32*)(cf + (n << 3) + kh + 2);
    a0 += xv * bfu(p0 & 0xffffu);
    a1 += xv * bfu(p0 >> 16);
    a2 += xv * bfu(p1 & 0xffffu);
    a3 += xv * bfu(p1 >> 16);
  }
  float* e = ebuf + ((size_t)(b * 128 + c) << 3) + kh;
  atomicAdd(e + 0, a0); atomicAdd(e + 1, a1);
  atomicAdd(e + 2, a2); atomicAdd(e + 3, a3);
}

// ====== softmax(max_k e - e) over k ======
__global__ void ccam_soft(const float* ebuf, float* abuf) {
  const int b = blockIdx.x, c = threadIdx.x;
  const float* e = ebuf + ((size_t)(b * 128 + c) << 3);
  float ev[8], m = -1e30f;
  #pragma unroll
  for (int k = 0; k < 8; ++k) { ev[k] = e[k]; m = fmaxf(m, ev[k]); }
  float mt = -1e30f;
  #pragma unroll
  for (int k = 0; k < 8; ++k) mt = fmaxf(mt, m - ev[k]);
  float s = 0.f, pk[8];
  #pragma unroll
  for (int k = 0; k < 8; ++k) { pk[k] = __expf(m - ev[k] - mt); s += pk[k]; }
  const float inv = 1.f / s;
  float* a = abuf + ((size_t)(b * 128 + c) << 3);
  #pragma unroll
  for (int k = 0; k < 8; ++k) a[k] = pk[k] * inv;
}

// ====== xs[n][c] = cb[n][c] + sc * sum_k a[c][k]*cf[n][k]  (bf16 NHWC) ======
__global__ void ccam_apply(const u16* cb, const u16* cf, const float* abuf,
                           const float* sc, u16* xs) {
  __shared__ float al[1024];
  const int t = threadIdx.x;
  const int gn0 = blockIdx.x * 128;
  const int b = gn0 >> 14;
  for (int i = t; i < 1024; i += 256) al[i] = abuf[(size_t)b * 1024 + i];
  __syncthreads();
  const int n = gn0 + (t >> 1), ch = (t & 1) * 64;
  const u16* crow = cb + ((size_t)n << 7) + ch;
  u16* xrow = xs + ((size_t)n << 7) + ch;
  const bf16x8 cf8 = *(const bf16x8*)(cf + ((size_t)n << 3));
  float cfv[8];
  #pragma unroll
  for (int k = 0; k < 8; ++k) cfv[k] = bfe(cf8, k);
  const float scv = sc[0];
  #pragma unroll
  for (int i = 0; i < 8; ++i) {
    const bf16x8 cv = *(const bf16x8*)(crow + i * 8);
    u32 o[4];
    #pragma unroll
    for (int jp = 0; jp < 4; ++jp) {
      float r[2];
      #pragma unroll
      for (int h = 0; h < 2; ++h) {
        const int j = jp * 2 + h;
        const float* ar = al + ((ch + i * 8 + j) << 3);
        float dec = 0.f;
        #pragma unroll
        for (int k = 0; k < 8; ++k) dec += ar[k] * cfv[k];
        r[h] = bfe(cv, j) + scv * dec;
      }
      o[jp] = (u32)f2bu(r[0]) | ((u32)f2bu(r[1]) << 16);
    }
    *(uint4*)(xrow + i * 8) = make_uint4(o[0], o[1], o[2], o[3]);
  }
}

// ====== row shunt: sr[b][j][h][c] = mean_{w4} qkv[b][h*128+w4*4+j][c] ======
__global__ void shunt_row(const u16* qkv, float* sr) {
  const int h = blockIdx.x, b = blockIdx.y;
  const int c0 = threadIdx.x * 2;
  float s0a = 0.f, s0b = 0.f, s1a = 0.f, s1b = 0.f;
  float s2a = 0.f, s2b = 0.f, s3a = 0.f, s3b = 0.f;
  for (int w4 = 0; w4 < 32; ++w4) {
    const u16* rp = qkv + ((size_t)(b * 16384 + h * 128 + w4 * 4) << 9) + c0;
    const u32 v0 = *(const u32*)(rp);
    const u32 v1 = *(const u32*)(rp + 512);
    const u32 v2 = *(const u32*)(rp + 1024);
    const u32 v3 = *(const u32*)(rp + 1536);
    s0a += bfu(v0 & 0xffffu); s0b += bfu(v0 >> 16);
    s1a += bfu(v1 & 0xffffu); s1b += bfu(v1 >> 16);
    s2a += bfu(v2 & 0xffffu); s2b += bfu(v2 >> 16);
    s3a += bfu(v3 & 0xffffu); s3b += bfu(v3 >> 16);
  }
  const float iv = 1.f / 32.f;
  *(float2*)(sr + ((size_t)((b * 4 + 0) * 128 + h) << 9) + c0) = make_float2(s0a * iv, s0b * iv);
  *(float2*)(sr + ((size_t)((b * 4 + 1) * 128 + h) << 9) + c0) = make_float2(s1a * iv, s1b * iv);
  *(float2*)(sr + ((size_t)((b * 4 + 2) * 128 + h) << 9) + c0) = make_float2(s2a * iv, s2b * iv);
  *(float2*)(sr + ((size_t)((b * 4 + 3) * 128 + h) << 9) + c0) = make_float2(s3a * iv, s3b * iv);
}

// ====== col shunt: sc[b][jc][w][c] = mean_{hr} qkv[b][(jc*32+hr)*128+w][c] ======
__global__ void shunt_col(const u16* qkv, float* scv) {
  const int wseg = blockIdx.x, jc = blockIdx.y, b = blockIdx.z;
  const int c0 = threadIdx.x * 2;
  for (int wl = 0; wl < 16; ++wl) {
    const int w = wseg * 16 + wl;
    float sa = 0.f, sb = 0.f;
    #pragma unroll 4
    for (int hr = 0; hr < 32; ++hr) {
      const u32 v = *(const u32*)(qkv + ((size_t)(b * 16384 + (jc * 32 + hr) * 128 + w) << 9) + c0);
      sa += bfu(v & 0xffffu); sb += bfu(v >> 16);
    }
    *(float2*)(scv + ((size_t)((b * 4 + jc) * 128 + w) << 9) + c0) =
        make_float2(sa * (1.f / 32.f), sb * (1.f / 32.f));
  }
}

// ============ axial attention; sall [b][jc][L][512] f32; out bf16 [b][512][256] ============
DEVFN float pinterp(const float* pos, int j, int ch, int col) {
  const float s = (col + 0.5f) * 0.125f - 0.5f;
  const float fl = floorf(s);
  const int i0 = (int)fl;
  const float f = s - fl;
  const int ia = i0 < 0 ? 0 : (i0 > 15 ? 15 : i0);
  const int i1 = i0 + 1;
  const int ib = i1 < 0 ? 0 : (i1 > 15 ? 15 : i1);
  const float* pp = pos + ((size_t)j * 128 + ch) * 16;
  return pp[ia] * (1.f - f) + pp[ib] * f;
}

__global__ void axial_k(const float* sall, const float* posq, const float* posk, u16* outp) {
  __shared__ float kl[16][132];
  __shared__ float vl[32][132];
  const int blk = blockIdx.x;
  const int h = blk & 7, jc = (blk >> 3) & 3, b = blk >> 5;
  const int r = threadIdx.x;  // 0..127
  const float* myrow = sall + ((size_t)((b * 4 + jc) * 128 + r) << 9);
  #pragma unroll
  for (int i = 0; i < 4; ++i) {
    const float4 kv = *(const float4*)(myrow + 128 + h * 16 + i * 4);
    kl[i * 4 + 0][r] = kv.x + pinterp(posk, jc, h * 16 + i * 4 + 0, r);
    kl[i * 4 + 1][r] = kv.y + pinterp(posk, jc, h * 16 + i * 4 + 1, r);
    kl[i * 4 + 2][r] = kv.z + pinterp(posk, jc, h * 16 + i * 4 + 2, r);
    kl[i * 4 + 3][r] = kv.w + pinterp(posk, jc, h * 16 + i * 4 + 3, r);
  }
  #pragma unroll
  for (int i = 0; i < 8; ++i) {
    const float4 vv = *(const float4*)(myrow + 256 + h * 32 + i * 4);
    vl[i * 4 + 0][r] = vv.x; vl[i * 4 + 1][r] = vv.y;
    vl[i * 4 + 2][r] = vv.z; vl[i * 4 + 3][r] = vv.w;
  }
  float q[16];
  #pragma unroll
  for (int i = 0; i < 4; ++i) {
    const float4 qv = *(const float4*)(myrow + h * 16 + i * 4);
    q[i * 4 + 0] = qv.x + pinterp(posq, jc, h * 16 + i * 4 + 0, r);
    q[i * 4 + 1] = qv.y + pinterp(posq, jc, h * 16 + i * 4 + 1, r);
    q[i * 4 + 2] = qv.z + pinterp(posq, jc, h * 16 + i * 4 + 2, r);
    q[i * 4 + 3] = qv.w + pinterp(posq, jc, h * 16 + i * 4 + 3, r);
  }
  __syncthreads();
  float m = -1e30f;
  for (int col = 0; col < 128; ++col) {
    float s = 0.f;
    #pragma unroll
    for (int kd = 0; kd < 16; ++kd) s += q[kd] * kl[kd][col];
    m = fmaxf(m, s * 0.25f);
  }
  float den = 0.f;
  float acc[32] = {};
  for (int col = 0; col < 128; ++col) {
    float s = 0.f;
    #pragma unroll
    for (int kd = 0; kd < 16; ++kd) s += q[kd] * kl[kd][col];
    const float pv = __expf(s * 0.25f - m);
    den += pv;
    #pragma unroll
    for (int d = 0; d < 32; ++d) acc[d] += pv * vl[d][col];
  }
  const float inv = 1.f / den;
  u16* ob = outp + (((size_t)(b * 512 + jc * 128 + r)) << 8) + h * 32;
  #pragma unroll
  for (int g8 = 0; g8 < 4; ++g8) {
    u32 o[4];
    #pragma unroll
    for (int jp = 0; jp < 4; ++jp) {
      const float a = fmaxf(acc[g8 * 8 + jp * 2 + 0] * inv, 0.f);
      const float bb = fmaxf(acc[g8 * 8 + jp * 2 + 1] * inv, 0.f);
      o[jp] = (u32)f2bu(a) | ((u32)f2bu(bb) << 16);
    }
    *(uint4*)(ob + g8 * 8) = make_uint4(o[0], o[1], o[2], o[3]);
  }
}

// ====== depthwise 3x3 + bn + relu, NHWC, one batch: qkv[b] -> dwout ======
__global__ void dw_k(const u16* qkv, const float* wd, const float* gd, const float* bd,
                     u16* dwout, int b) {
  const int xseg = blockIdx.x, y = blockIdx.y;
  const int c0 = threadIdx.x * 2;
  float w0[9], w1[9];
  #pragma unroll
  for (int tap = 0; tap < 9; ++tap) {
    w0[tap] = wd[c0 * 9 + tap];
    w1[tap] = wd[(c0 + 1) * 9 + tap];
  }
  const float g0 = gd[c0], g1 = gd[c0 + 1], b0 = bd[c0], b1 = bd[c0 + 1];
  for (int xl = 0; xl < 32; ++xl) {
    const int x = xseg * 32 + xl;
    float s0 = 0.f, s1 = 0.f;
    #pragma unroll
    for (int dy = -1; dy <= 1; ++dy) {
      const int yy = y + dy;
      if ((unsigned)yy < 128u) {
        #pragma unroll
        for (int dxi = -1; dxi <= 1; ++dxi) {
          const int xx = x + dxi;
          if ((unsigned)xx < 128u) {
            const u32 v = *(const u32*)(qkv + ((size_t)(b * 16384 + yy * 128 + xx) << 9) + c0);
            const int tap = (dy + 1) * 3 + dxi + 1;
            s0 += w0[tap] * bfu(v & 0xffffu);
            s1 += w1[tap] * bfu(v >> 16);
          }
        }
      }
    }
    const float o0 = fmaxf(g0 * s0 + b0, 0.f);
    const float o1 = fmaxf(g1 * s1 + b1, 0.f);
    *(u32*)(dwout + ((size_t)(y * 128 + x) << 9) + c0) = (u32)f2bu(o0) | ((u32)f2bu(o1) << 16);
  }
}

// =====================================================================
extern "C" void kernel_launch(void* const* d_in, const int* in_sizes, int n_in,
                              void* d_out, int out_size, void* d_ws, size_t ws_size,
                              hipStream_t stream) {
  const float* x   = (const float*)d_in[0];
  const float* wcc = (const float*)d_in[1];
  const float* gcc = (const float*)d_in[2];
  const float* bcc = (const float*)d_in[3];
  const float* wen = (const float*)d_in[4];
  const float* gen = (const float*)d_in[5];
  const float* ben = (const float*)d_in[6];
  const float* sc  = (const float*)d_in[7];
  const float* wq  = (const float*)d_in[8];
  const float* gq  = (const float*)d_in[9];
  const float* bq  = (const float*)d_in[10];
  const float* wk  = (const float*)d_in[11];
  const float* gk  = (const float*)d_in[12];
  const float* bk  = (const float*)d_in[13];
  const float* wv  = (const float*)d_in[14];
  const float* gv  = (const float*)d_in[15];
  const float* bv  = (const float*)d_in[16];
  const float* wd  = (const float*)d_in[17];
  const float* gd  = (const float*)d_in[18];
  const float* bd  = (const float*)d_in[19];
  const float* wp  = (const float*)d_in[20];
  const float* gp  = (const float*)d_in[21];
  const float* bp  = (const float*)d_in[22];
  const float* wr  = (const float*)d_in[23];
  const float* gr  = (const float*)d_in[24];
  const float* brr = (const float*)d_in[25];
  const float* wc2 = (const float*)d_in[26];
  const float* gc2 = (const float*)d_in[27];
  const float* bc2 = (const float*)d_in[28];
  const float* wo  = (const float*)d_in[29];
  const float* go  = (const float*)d_in[30];
  const float* bo  = (const float*)d_in[31];
  const float* prq = (const float*)d_in[32];
  const float* prk = (const float*)d_in[33];
  const float* pcq = (const float*)d_in[34];
  const float* pck = (const float*)d_in[35];

  char* ws = (char*)d_ws;
  const size_t P = 134217728;
  // ---- workspace map (total used 204,083,200 <= 205,819,904 known-good) ----
  u16*   qkv    = (u16*)ws;                       // [8][16384][512] bf16, t6..end
  u16*   Wp3    = (u16*)(ws + 67108864);          // inside qkv region, dead before t6
  u16*   cb     = (u16*)(ws + P);                 // [8][16384][128] bf16, t2-5
  float* sr_all = (float*)(ws + P);               // [8][4][128][512] f32, t7-8 (cb dead)
  float* sc_all = (float*)(ws + P + 8388608);
  u16*   dwout  = (u16*)(ws + P);                 // [16384][512] bf16 per-batch, t10 (sr/sc dead)
  u16*   xr_cv  = (u16*)(ws + P + 16777216);      // [8][512][256] bf16
  u16*   xc_cv  = (u16*)(ws + P + 18874368);
  u16*   xr_lin = (u16*)(ws + P + 20971520);
  u16*   xc_lin = (u16*)(ws + P + 23068672);
  u16*   xt     = (u16*)(ws + P + 33554432);      // [8][128][128][64] bf16, t1-2
  u16*   cfb    = (u16*)(ws + P + 33554432);      // [8][16384][8] bf16, t3-5 (xt dead)
  u16*   xs     = (u16*)(ws + P + 35651584);      // [8][16384][128] bf16, t5-6
  u16*   qkvp   = (u16*)(ws + P + 35651584);      // same slot, t10-12 (xs dead)
  char*  WT     = ws + P + 69206016;
  u16*   Wqkv   = (u16*)(WT);
  u16*   Wwp    = (u16*)(WT + 131072);
  u16*   Wwr    = (u16*)(WT + 262144);
  u16*   Wwc    = (u16*)(WT + 393216);
  u16*   Wwo    = (u16*)(WT + 524288);
  float* gqkv   = (float*)(WT + 589824);
  float* bqkv   = (float*)(WT + 591872);
  float* ebuf   = (float*)(WT + 593920);
  float* abuf   = (float*)(WT + 626688);
  float* out    = (float*)d_out;

  // t1: pack weights (+zero ebuf) and transpose input to NHWC
  pack_k<<<1476, 256, 0, stream>>>(wcc, wq, wk, wv, gq, gk, gv, bq, bk, bv,
                                   wp, wr, wc2, wo, Wp3, Wqkv, Wwp, Wwr, Wwc, Wwo,
                                   gqkv, bqkv, ebuf);
  xt_k<<<dim3(128, 8), 256, 0, stream>>>(x, xt);

  // t2: cb = relu(bn(conv3x3(x)))
  { GP p{}; p.X = xt; p.W = Wp3; p.gain = gcc; p.bias = bcc; p.out = cb;
    p.K = 576; p.NX = 16384; p.CO = 128;
    gmm<1, 1, 0><<<dim3(128, 2, 8), 256, 0, stream>>>(p); }

  // t3-5: CCAM
  cf_k<<<512, 256, 0, stream>>>(cb, wen, gen, ben, cfb);
  ccam_e<<<dim3(32, 8), 256, 0, stream>>>(cb, cfb, ebuf);
  ccam_soft<<<8, 128, 0, stream>>>(ebuf, abuf);
  ccam_apply<<<1024, 256, 0, stream>>>(cb, cfb, abuf, sc, xs);

  // t6: qkv = bn(conv1x1(xs, [wq;wk;wv]))
  { GP p{}; p.X = xs; p.W = Wqkv; p.gain = gqkv; p.bias = bqkv; p.out = qkv;
    p.K = 128; p.NX = 16384; p.CO = 512;
    gmm<0, 0, 0><<<dim3(128, 8, 8), 256, 0, stream>>>(p); }

  // t7: shunts
  shunt_row<<<dim3(128, 8), 256, 0, stream>>>(qkv, sr_all);
  shunt_col<<<dim3(8, 4, 8), 256, 0, stream>>>(qkv, sc_all);

  // t8-9: axial attentions + their 1x1 convs
  axial_k<<<256, 128, 0, stream>>>(sr_all, prq, prk, xr_lin);
  axial_k<<<256, 128, 0, stream>>>(sc_all, pcq, pck, xc_lin);
  { GP p{}; p.X = xr_lin; p.W = Wwr; p.gain = gr; p.bias = brr; p.out = xr_cv;
    p.K = 256; p.NX = 512; p.CO = 256;
    gmm<0, 0, 0><<<dim3(4, 4, 8), 256, 0, stream>>>(p); }
  { GP p{}; p.X = xc_lin; p.W = Wwc; p.gain = gc2; p.bias = bc2; p.out = xc_cv;
    p.K = 256; p.NX = 512; p.CO = 256;
    gmm<0, 0, 0><<<dim3(4, 4, 8), 256, 0, stream>>>(p); }

  // t10-11: per-batch depthwise + wp GEMM -> qkvp
  for (int bi = 0; bi < 8; ++bi) {
    dw_k<<<dim3(4, 128), 256, 0, stream>>>(qkv, wd, gd, bd, dwout, bi);
    GP p{}; p.X = dwout; p.W = Wwp; p.gain = gp; p.bias = bp; p.out = qkvp;
    p.K = 512; p.NX = 16384; p.CO = 128; p.b0 = bi;
    gmm<0, 0, 1><<<dim3(128, 2, 1), 256, 0, stream>>>(p);
  }

  // t12: out = hsigmoid(bn(conv1x1(relu(xr+xc+v), wo))) * qkvp  -> NCHW f32
  { GP p{}; p.Xv = qkv; p.Xr = xr_cv; p.Xc = xc_cv; p.W = Wwo;
    p.gain = go; p.bias = bo; p.auxh = qkvp; p.outf = out;
    p.K = 256; p.NX = 16384; p.CO = 128;
    gmm<2, 2, 0><<<dim3(128, 2, 8), 256, 0, stream>>>(p); }
}